// Round 1
// baseline (843.477 us; speedup 1.0000x reference)
//
#include <hip/hip_runtime.h>
#include <stdint.h>

#define B_    8192
#define N_    40
#define F_    256
#define NBLK_ 4
#define BLK_  10
#define M_    (B_*N_)     /* 327680 rows               */
#define NF_   (N_*F_)     /* 10240 features for BN     */
#define BG_   8           /* batches per fused workgroup */
#define ROWS_ (BG_*BLK_)  /* 80 output rows per workgroup */

using frag_t = __attribute__((ext_vector_type(8))) short;   // 8 bf16 (4 VGPRs)
using f32x4  = __attribute__((ext_vector_type(4))) float;   // MFMA C/D

__device__ __forceinline__ unsigned short f2b(float x){
  unsigned int u = __float_as_uint(x);
  u += 0x7FFF + ((u >> 16) & 1);          // round-to-nearest-even
  return (unsigned short)(u >> 16);
}
__device__ __forceinline__ float b2f(unsigned short h){
  return __uint_as_float(((unsigned int)h) << 16);
}

// ---------------------------------------------------------------------------
// K0: Wt[f][k] = bf16(W[k][f]) (transposed so MFMA B-fragments are contiguous
//     16B loads), and zero the sum/sumsq accumulators (ws is poisoned).
__global__ __launch_bounds__(256) void k_prep(const float* __restrict__ W,
                                              unsigned short* __restrict__ Wt,
                                              float* __restrict__ sums){
  int id = blockIdx.x*256 + threadIdx.x;   // 0..65535
  int f = id >> 8, k = id & 255;
  Wt[f*256 + k] = f2b(W[k*256 + f]);
  if (id < 2*NF_) sums[id] = 0.f;
}

// ---------------------------------------------------------------------------
// K1 (fused aprime+gemm+stats): one workgroup = 8 batches x one 10-row block.
//  phase A: stage 10x10 adj blocks (padded rows of 12 so coeff reads are
//           float4/float2)
//  phase B: A' = adj_blk @ input_blk  -> LDS bf16 [80][256] (row pad 264 so
//           MFMA frag reads keep the verified stride-4-dword bank pattern)
//  phase C: 16x16x32 bf16 MFMA, [80][256] @ Wt -> acc (frag layouts identical
//           to the previously-verified k_gemm)
//  phase D: acc -> LDS bf16; per-(n,f) sum/sumsq over the 8 batches in
//           registers -> 20 coalesced atomicAdds/thread; blk tile -> global
//           as uint4 (8 bf16 per store).
__global__ __launch_bounds__(256, 2) void k_fused(const float* __restrict__ input,
                                                  const float* __restrict__ adj,
                                                  const unsigned short* __restrict__ Wt,
                                                  unsigned short* __restrict__ A,
                                                  float* __restrict__ sums){
  __shared__ __align__(16) float sadjp[BG_][BLK_][12];     // 3.84 KB
  __shared__ __align__(16) unsigned short As[ROWS_][264];  // 41.25 KB

  const int t  = threadIdx.x;
  const int wg = blockIdx.x;
  const int b0 = (wg >> 2) * BG_;          // batch group base
  const int s  = (wg & 3) * BLK_;          // block row offset 0/10/20/30

  // ---- phase A: adj diagonal blocks -> LDS (800 floats) ----
  for (int i = t; i < BG_*100; i += 256){
    int bl = i / 100, r = i - bl*100;
    int n = r / 10, j = r - n*10;
    sadjp[bl][n][j] = adj[(size_t)(b0+bl)*(N_*N_) + (s+n)*N_ + (s+j)];
  }
  __syncthreads();

  // ---- phase B: A' into LDS. thread = (bl = t>>5, u = t&31), f = kh*128+u*4
  {
    const int bl = t >> 5, u = t & 31;
    const float* ip0 = input + ((size_t)(b0+bl)*N_ + s)*F_ + u*4;
    #pragma unroll
    for (int kh = 0; kh < 2; ++kh){
      float4 x[BLK_];
      #pragma unroll
      for (int j = 0; j < BLK_; ++j)
        x[j] = *(const float4*)(ip0 + kh*128 + j*F_);      // coalesced 16B
      #pragma unroll
      for (int n = 0; n < BLK_; ++n){
        const float4 cA = *(const float4*)(&sadjp[bl][n][0]);
        const float4 cB = *(const float4*)(&sadjp[bl][n][4]);
        const float2 cC = *(const float2*)(&sadjp[bl][n][8]);
        const float c[10] = {cA.x,cA.y,cA.z,cA.w,cB.x,cB.y,cB.z,cB.w,cC.x,cC.y};
        float ax=0.f, ay=0.f, az=0.f, aw=0.f;
        #pragma unroll
        for (int j = 0; j < BLK_; ++j){
          ax += c[j]*x[j].x; ay += c[j]*x[j].y;
          az += c[j]*x[j].z; aw += c[j]*x[j].w;
        }
        uint2 p;
        p.x = (unsigned)f2b(ax) | ((unsigned)f2b(ay) << 16);
        p.y = (unsigned)f2b(az) | ((unsigned)f2b(aw) << 16);
        *(uint2*)(&As[bl*BLK_ + n][kh*128 + u*4]) = p;     // 8B LDS write
      }
    }
  }
  __syncthreads();

  // ---- phase C: MFMA. wave w owns cols w*64..w*64+63, all 80 rows ----
  const int lane = t & 63, wave = t >> 6;
  const int wc   = wave * 64;
  const int lm   = lane & 15;              // m (A) / n (B) within 16x16 tile
  const int lq   = lane >> 4;              // quad 0..3
  const int lk8  = lq * 8;                 // k offset of this lane's 8 elems

  f32x4 acc[5][4];
  #pragma unroll
  for (int i = 0; i < 5; ++i)
    #pragma unroll
    for (int j = 0; j < 4; ++j)
      acc[i][j] = (f32x4){0.f, 0.f, 0.f, 0.f};

  #pragma unroll
  for (int kh = 0; kh < 2; ++kh){
    #pragma unroll
    for (int kc = 0; kc < 4; ++kc){
      frag_t av[5], bv[4];
      #pragma unroll
      for (int rt = 0; rt < 5; ++rt)
        av[rt] = *(const frag_t*)(&As[rt*16 + lm][kh*128 + kc*32 + lk8]);
      const unsigned short* wp = Wt + (size_t)(wc + lm)*256 + kh*128 + kc*32 + lk8;
      #pragma unroll
      for (int ct = 0; ct < 4; ++ct)
        bv[ct] = *(const frag_t*)(wp + ct*16*256);         // L2-resident
      #pragma unroll
      for (int rt = 0; rt < 5; ++rt)
        #pragma unroll
        for (int ct = 0; ct < 4; ++ct)
          acc[rt][ct] = __builtin_amdgcn_mfma_f32_16x16x32_bf16(av[rt], bv[ct], acc[rt][ct], 0, 0, 0);
    }
  }
  __syncthreads();                         // all MFMA reads of As done

  // ---- phase D1: blk (bf16) -> LDS (C/D layout: col=lane&15, row=lq*4+reg)
  #pragma unroll
  for (int rt = 0; rt < 5; ++rt)
    #pragma unroll
    for (int ct = 0; ct < 4; ++ct)
      #pragma unroll
      for (int r = 0; r < 4; ++r)
        As[rt*16 + lq*4 + r][wc + ct*16 + lm] = f2b(acc[rt][ct][r]);
  __syncthreads();

  // ---- phase D2: stats for feature (s+n, f=t) over the 8 batches ----
  float sm[BLK_], sq[BLK_];
  #pragma unroll
  for (int n = 0; n < BLK_; ++n){ sm[n] = 0.f; sq[n] = 0.f; }
  #pragma unroll
  for (int bl = 0; bl < BG_; ++bl)
    #pragma unroll
    for (int n = 0; n < BLK_; ++n){
      float v = b2f(As[bl*BLK_ + n][t]);   // bf16-rounded, matches old k_stats
      sm[n] += v; sq[n] += v*v;
    }
  #pragma unroll
  for (int n = 0; n < BLK_; ++n){
    atomicAdd(&sums[(s+n)*F_ + t],        sm[n]);   // wave-coalesced
    atomicAdd(&sums[NF_ + (s+n)*F_ + t],  sq[n]);
  }

  // ---- phase D3: blk tile -> global, uint4 (8 bf16) per store ----
  #pragma unroll
  for (int i = 0; i < 10; ++i){
    int c   = i*256 + t;                   // 0..2559 chunk id
    int row = c >> 5, cc = (c & 31)*8;
    int q   = row / BLK_, rm = row - q*BLK_;
    uint4 v = *(const uint4*)(&As[row][cc]);
    *(uint4*)(A + ((size_t)(b0 + q)*N_ + s + rm)*F_ + cc) = v;
  }
}

// ---------------------------------------------------------------------------
// K2: per-feature affine. Zero-feature blocks contribute exactly beta, so
// t = sum_i beta[i][nf] - mean*s ; s = gamma[n/10][nf]*rsqrt(var+eps).
__global__ __launch_bounds__(256) void k_finalize(const float* __restrict__ sums,
                                                  const float* __restrict__ gamma,
                                                  const float* __restrict__ beta,
                                                  float* __restrict__ st){
  int nf = blockIdx.x*256 + threadIdx.x;   // 0..10239
  int n = nf >> 8;
  int blki = n / 10;
  float mean = sums[nf] * (1.f/8192.f);
  float var  = sums[NF_ + nf] * (1.f/8192.f) - mean*mean;  // biased var
  float sc = gamma[blki*NF_ + nf] * rsqrtf(var + 1e-5f);
  float tt = -mean * sc;
  #pragma unroll
  for (int i = 0; i < 4; ++i) tt += beta[i*NF_ + nf];
  st[nf] = sc;
  st[NF_ + nf] = tt;
}

// ---------------------------------------------------------------------------
// K3: out[b,n,f] = blk*s[nf] + t[nf]  (fp32 out, 8 elems/thread)
__global__ __launch_bounds__(256) void k_norm(const unsigned short* __restrict__ A,
                                              const float* __restrict__ st,
                                              float* __restrict__ out){
  size_t idx = ((size_t)blockIdx.x*256 + threadIdx.x) * 8;
  uint4 raw = *(const uint4*)(A + idx);
  int nf = (int)(idx % NF_);               // 8-aligned, 10240 % 8 == 0
  const float4 s0 = *(const float4*)(st + nf);
  const float4 s1 = *(const float4*)(st + nf + 4);
  const float4 t0 = *(const float4*)(st + NF_ + nf);
  const float4 t1 = *(const float4*)(st + NF_ + nf + 4);
  float4 o0, o1;
  o0.x = b2f((unsigned short)(raw.x & 0xFFFF)) * s0.x + t0.x;
  o0.y = b2f((unsigned short)(raw.x >> 16))    * s0.y + t0.y;
  o0.z = b2f((unsigned short)(raw.y & 0xFFFF)) * s0.z + t0.z;
  o0.w = b2f((unsigned short)(raw.y >> 16))    * s0.w + t0.w;
  o1.x = b2f((unsigned short)(raw.z & 0xFFFF)) * s1.x + t1.x;
  o1.y = b2f((unsigned short)(raw.z >> 16))    * s1.y + t1.y;
  o1.z = b2f((unsigned short)(raw.w & 0xFFFF)) * s1.z + t1.z;
  o1.w = b2f((unsigned short)(raw.w >> 16))    * s1.w + t1.w;
  *(float4*)(out + idx)     = o0;
  *(float4*)(out + idx + 4) = o1;
}

// ---------------------------------------------------------------------------
extern "C" void kernel_launch(void* const* d_in, const int* in_sizes, int n_in,
                              void* d_out, int out_size, void* d_ws, size_t ws_size,
                              hipStream_t stream){
  const float* input = (const float*)d_in[0];
  const float* adj   = (const float*)d_in[1];
  const float* W     = (const float*)d_in[2];
  const float* gamma = (const float*)d_in[3];
  const float* beta  = (const float*)d_in[4];
  float* out = (float*)d_out;

  char* ws = (char*)d_ws;
  unsigned short* A  = (unsigned short*)ws;                         // M*256 bf16 (blk)
  unsigned short* Wt = (unsigned short*)(ws + (size_t)M_*256*2);    // 256x256 bf16 (transposed)
  float* sums = (float*)(ws + (size_t)M_*256*2 + 256*256*2);        // 2*NF fp32
  float* st   = sums + 2*NF_;                                       // 2*NF fp32 (s, t)

  k_prep    <<<256,             256, 0, stream>>>(W, Wt, sums);
  k_fused   <<<(B_/BG_)*NBLK_,  256, 0, stream>>>(input, adj, Wt, A, sums);
  k_finalize<<<NF_/256,         256, 0, stream>>>(sums, gamma, beta, st);
  k_norm    <<<(int)(((size_t)M_*256)/2048), 256, 0, stream>>>(A, st, out);
}